// Round 4
// baseline (190.129 us; speedup 1.0000x reference)
//
#include <hip/hip_runtime.h>

#define N_WT_     10
#define WT_LEN_   512
#define FIR_TAPS_ 31
#define N_REFL_   15
#define B_        16
#define L_        160000

constexpr int   TPB   = 256;
constexpr int   TPS   = 1024;          // scan block size
constexpr float INCF  = 0.032f;        // f32(512/16000), jax weak-typed scalar
constexpr int   NG0   = L_ / 16;       // 10000 level-0 groups (of 16 samples)
constexpr int   NG1   = NG0 / 16;      // 625 level-1 groups
constexpr int   NG2   = 40;            // ceil(625/16), pad 625->640
constexpr int   NG3   = 3;             // ceil(40/16),  pad 40->48
constexpr int   CPB   = 5;             // samples per thread in synth
constexpr int   WTI   = (WT_LEN_ + 1) * N_WT_;  // 513*10 interleaved (+dup row 0)

// ---------------------------------------------------------------------------
// Kernel 1: level-0 group sums, LDS-free for the sums. Each thread owns one
// group of 16: 4x float4 loads (lane-private 64B line), then the sequential
// f32 fold. The empty asm() blocks fp-contraction so the INCF*pitch multiply
// stays separately rounded. FIR filter fused into the first 10 blocks of row
// b==0; wt2 written INTERLEAVED: wt2[i*10+w], row 512 duplicating row 0
// (20520 B -> fits L1/LDS; synth stages it once per block).
// ---------------------------------------------------------------------------
__global__ __launch_bounds__(TPB) void ysum_kernel(
        const float* __restrict__ pitch, float* __restrict__ y,
        const float* __restrict__ wavetables, const float* __restrict__ fir_h,
        float* __restrict__ wt2) {
    __shared__ float s_pad[WT_LEN_ + 2 * N_REFL_];
    __shared__ float s_h[FIR_TAPS_];
    const int b = blockIdx.y, bx = blockIdx.x, t = threadIdx.x;

    const bool do_fir = (b == 0) && (bx < N_WT_);   // uniform per block
    if (do_fir) {
        if (t < FIR_TAPS_) s_h[t] = fir_h[t];
        for (int j = t; j < WT_LEN_ + 2 * N_REFL_; j += TPB) {
            int src = (j + WT_LEN_ - N_REFL_) % WT_LEN_;
            s_pad[j] = wavetables[bx * WT_LEN_ + src];
        }
        __syncthreads();   // block-uniform condition: safe
        for (int i = t; i < WT_LEN_; i += TPB) {   // i = t and t+256
            float acc = 0.0f;
#pragma unroll
            for (int tap = 0; tap < FIR_TAPS_; ++tap)
                acc = fmaf(s_h[tap], s_pad[i + tap], acc);
            wt2[i * N_WT_ + bx] = acc;
            if (i == 0) wt2[WT_LEN_ * N_WT_ + bx] = acc;  // dup row 0 at row 512
        }
    }

    const int g = bx * 256 + t;
    if (g < NG0) {
        const float4* p4 = (const float4*)(pitch + (size_t)b * L_ + (size_t)g * 16);
        float4 v0 = p4[0], v1 = p4[1], v2 = p4[2], v3 = p4[3];
        float xs[16] = {v0.x, v0.y, v0.z, v0.w, v1.x, v1.y, v1.z, v1.w,
                        v2.x, v2.y, v2.z, v2.w, v3.x, v3.y, v3.z, v3.w};
        float acc = 0.0f;
#pragma unroll
        for (int i = 0; i < 16; ++i) {
            float inc = INCF * xs[i];
            asm("" : "+v"(inc));       // forbid mul+add contraction
            acc += inc;                // sequential f32 fold
        }
        y[b * NG0 + g] = acc;
    }
}

// ---------------------------------------------------------------------------
// Kernel 2: per-row hierarchical scan (base 16, sequential inner folds),
// running folds == bit-identical to per-endpoint from-scratch folds.
// Materializes S1 so synth pays one near-broadcast coalesced load per sample.
// ---------------------------------------------------------------------------
__global__ __launch_bounds__(TPS) void scan_kernel(
        const float* __restrict__ y, float* __restrict__ S1) {
    __shared__ __align__(16) float s_y[NG0];    // 40 KB
    __shared__ __align__(16) float s_S1[NG0];   // 40 KB
    __shared__ float s_z[NG1];
    __shared__ float s_S2[NG1];
    __shared__ float s_w[NG2], s_S3[NG2];
    __shared__ float s_v[NG3], s_S4[NG3];
    const int b = blockIdx.x, t = threadIdx.x;
    const float* yrow = y + (size_t)b * NG0;
    {   // vectorized row load (NG0 even, row byte offset % 8 == 0)
        const float2* src = (const float2*)yrow;
        float2* dst = (float2*)s_y;
        for (int i = t; i < NG0 / 2; i += TPS) dst[i] = src[i];
    }
    __syncthreads();
    for (int j = t; j < NG1; j += TPS) {
        float a = 0.0f;
        for (int i = 0; i < 16; ++i) a += s_y[16 * j + i];
        s_z[j] = a;
    }
    __syncthreads();
    if (t < NG2) {
        float a = 0.0f;
        int hi = min(16 * t + 16, NG1);
        for (int i = 16 * t; i < hi; ++i) a += s_z[i];
        s_w[t] = a;
    }
    __syncthreads();
    if (t < NG3) {
        float a = 0.0f;
        int hi = min(16 * t + 16, NG2);
        for (int i = 16 * t; i < hi; ++i) a += s_w[i];
        s_v[t] = a;
    }
    __syncthreads();
    if (t == 0) {
        float run = 0.0f;
        for (int m = 0; m < NG3; ++m) { run += s_v[m]; s_S4[m] = run; }
    }
    __syncthreads();
    if (t < NG2) {
        float a = 0.0f;
        for (int i = (t >> 4) << 4; i <= t; ++i) a += s_w[i];
        if (t >= 16) a = a + s_S4[(t >> 4) - 1];
        s_S3[t] = a;
    }
    __syncthreads();
    if (t < NG2) {
        float r = 0.0f;
        float carry = (t > 0) ? s_S3[t - 1] : 0.0f;
        int hi = min(16 * t + 16, NG1);
        for (int k = 16 * t; k < hi; ++k) {
            r += s_z[k];
            s_S2[k] = (t > 0) ? r + carry : r;
        }
    }
    __syncthreads();
    for (int j = t; j < NG1; j += TPS) {
        float r = 0.0f;
        float carry = (j > 0) ? s_S2[j - 1] : 0.0f;
        for (int k = 0; k < 16; ++k) {
            r += s_y[16 * j + k];
            s_S1[16 * j + k] = (j > 0) ? r + carry : r;
        }
    }
    __syncthreads();
    float* S1row = S1 + (size_t)b * NG0;
    {   // vectorized row store
        const float2* src = (const float2*)s_S1;
        float2* dst = (float2*)S1row;
        for (int i = t; i < NG0 / 2; i += TPS) dst[i] = src[i];
    }
}

// ---------------------------------------------------------------------------
// Kernel 3: synth — 5 samples/thread (grid 125 x 16 = 2000 blocks, all
// co-resident). Wavetable gather from LDS (ds_read, off the vector-memory
// path; staging amortized to 16 B/sample, one barrier per 1280 samples).
// Register double-buffering: sample cc+1's 14 global loads issue before
// sample cc's compute consumes its values; sample-0 loads issue before the
// staging loop. All arithmetic textually identical to the round-2 kernel.
// ---------------------------------------------------------------------------
struct SIn {
    float  pv, p0, env, carry;
    float2 a0, a1, a2, a3, a4;
};

__device__ __forceinline__ SIn load_in(int l, size_t rowb,
        const float* __restrict__ pitch, const float* __restrict__ envelope,
        const float* __restrict__ attention, const float* __restrict__ S1row) {
    SIn s;
    const size_t g = rowb + l;
    s.pv  = pitch[g];                    // own increment source
    s.p0  = pitch[l];                    // batch-row-0 quirk (increment[0])
    s.env = envelope[g];
    const int g0 = l >> 4;
    s.carry = (g0 > 0) ? S1row[g0 - 1] : 0.0f;
    const float2* ap = (const float2*)(attention + g * (size_t)N_WT_);
    s.a0 = ap[0]; s.a1 = ap[1]; s.a2 = ap[2]; s.a3 = ap[3]; s.a4 = ap[4];
    return s;
}

__global__ __launch_bounds__(TPB) void synth_kernel(
        const float* __restrict__ pitch,
        const float* __restrict__ envelope,
        const float* __restrict__ attention,
        const float* __restrict__ wt2,
        const float* __restrict__ S1,
        float* __restrict__ out) {
    __shared__ __align__(8) float s_wt[WTI];  // 513*10 floats = 20520 B
    const int b = blockIdx.y, cb = blockIdx.x, t = threadIdx.x;
    const size_t rowb = (size_t)b * L_;
    const float* S1row = S1 + (size_t)b * NG0;
    const int l0 = cb * (TPB * CPB) + t;

    // sample-0 loads issue before staging (independent of it)
    SIn cur = load_in(l0, rowb, pitch, envelope, attention, S1row);

    {   // stage interleaved wavetable to LDS (float2: WTI = 5130 even)
        const float2* src = (const float2*)wt2;
        float2* dst = (float2*)s_wt;
        for (int i = t; i < WTI / 2; i += TPB) dst[i] = src[i];
    }
    __syncthreads();  // the only barrier

    const int lane  = t & 63;
    const int r16   = lane & 15;
    const int sbase = lane & ~15;

#pragma unroll
    for (int cc = 0; cc < CPB; ++cc) {
        SIn nxt = cur;
        if (cc + 1 < CPB)   // issue next sample's loads before consuming cur
            nxt = load_in(l0 + (cc + 1) * TPB, rowb, pitch, envelope,
                          attention, S1row);
        const int l = l0 + cc * TPB;

        float x = INCF * cur.pv;  // f32 increment, separately rounded
        // sequential in-group-of-16 fold via shuffles (bit-exact association;
        // +0.0f predicated adds exact: all partials > 0 since pitch >= 100 Hz)
        float acc = 0.0f;
#pragma unroll
        for (int k = 0; k < 16; ++k) {
            float v = __shfl(x, sbase + k, 64);
            acc += (k <= r16) ? v : 0.0f;
        }
        const int g0 = l >> 4;
        if (g0 > 0) acc = acc + cur.carry;   // carry add

        float idx = acc - INCF * cur.p0;     // minus increment[0] (batch row 0)
        float r = fmodf(idx, 512.0f);        // lax.rem (exact for y=512)
        if (r < 0.0f) r += 512.0f;           // jnp.remainder sign fixup
        if (512.0f - r < 1e-5f) r = 0.0f;    // the reference's snap
        float fl = floorf(r);
        float alpha = r - fl;
        int lo = (int)fl;

        // rows lo, lo+1 = 20 contiguous floats in LDS (row 512 dups row 0)
        const float2* pw = (const float2*)(s_wt + lo * N_WT_);
        float2 q0 = pw[0], q1 = pw[1], q2 = pw[2], q3 = pw[3], q4 = pw[4];
        float2 q5 = pw[5], q6 = pw[6], q7 = pw[7], q8 = pw[8], q9 = pw[9];
        float loV[10] = {q0.x, q0.y, q1.x, q1.y, q2.x, q2.y, q3.x, q3.y, q4.x, q4.y};
        float hiV[10] = {q5.x, q5.y, q6.x, q6.y, q7.x, q7.y, q8.x, q8.y, q9.x, q9.y};
        float a[10] = {cur.a0.x, cur.a0.y, cur.a1.x, cur.a1.y, cur.a2.x,
                       cur.a2.y, cur.a3.x, cur.a3.y, cur.a4.x, cur.a4.y};

        float a0 = 0.0f;
#pragma unroll
        for (int w = 0; w < N_WT_; ++w)
            a0 += a[w] * (loV[w] + alpha * (hiV[w] - loV[w]));
        out[rowb + l] = a0 * cur.env;

        cur = nxt;
    }
}

// ---------------------------------------------------------------------------
extern "C" void kernel_launch(void* const* d_in, const int* in_sizes, int n_in,
                              void* d_out, int out_size, void* d_ws, size_t ws_size,
                              hipStream_t stream) {
    const float* pitch      = (const float*)d_in[0];  // (B, L, 1)
    const float* envelope   = (const float*)d_in[1];  // (B, L, 1)
    const float* attention  = (const float*)d_in[2];  // (B, L, 10)
    const float* wavetables = (const float*)d_in[3];  // (10, 512)
    const float* fir_h      = (const float*)d_in[4];  // (31,)
    float*       out        = (float*)d_out;          // (B, L, 1)

    char*  ws  = (char*)d_ws;
    float* wt2 = (float*)(ws);                         // 20520 B (reserve 32 KiB)
    float* y   = (float*)(ws + 32768);                 // 16*10000*4 = 640 KB
    float* S1  = (float*)(ws + 32768 + 655360);        // 640 KB

    ysum_kernel<<<dim3(40, B_), dim3(TPB), 0, stream>>>(
        pitch, y, wavetables, fir_h, wt2);
    scan_kernel<<<dim3(B_), dim3(TPS), 0, stream>>>(y, S1);
    synth_kernel<<<dim3(L_ / (TPB * CPB), B_), dim3(TPB), 0, stream>>>(
        pitch, envelope, attention, wt2, S1, out);
}

// Round 5
// 189.953 us; speedup vs baseline: 1.0009x; 1.0009x over previous
//
#include <hip/hip_runtime.h>

#define N_WT_     10
#define WT_LEN_   512
#define FIR_TAPS_ 31
#define N_REFL_   15
#define B_        16
#define L_        160000

constexpr int   TPB   = 256;
constexpr int   TPS   = 1024;          // scan block size
constexpr float INCF  = 0.032f;        // f32(512/16000), jax weak-typed scalar
constexpr int   NG0   = L_ / 16;       // 10000 level-0 groups (of 16 samples)
constexpr int   NG1   = NG0 / 16;      // 625 level-1 groups
constexpr int   NG2   = 40;            // ceil(625/16), pad 625->640
constexpr int   NG3   = 3;             // ceil(40/16),  pad 40->48
constexpr int   WROW  = 12;            // padded row width: 48 B -> 16B-aligned rows

// ---------------------------------------------------------------------------
// Kernel 1: level-0 group sums, LDS-free for the sums. Each thread owns one
// group of 16: 4x float4 loads (lane-private 64B line), then the sequential
// f32 fold. The empty asm() blocks fp-contraction so the INCF*pitch multiply
// stays separately rounded. FIR filter fused into the first 10 blocks of row
// b==0; wt4 written INTERLEAVED with 12-float (48 B) padded rows:
// wt4[i*12+w], w<10, row 512 duplicating row 0. 513*48 = 24.6 KB -> still
// L1-resident; 48*lo is 16B-aligned for all lo -> synth gathers 6x float4.
// ---------------------------------------------------------------------------
__global__ __launch_bounds__(TPB) void ysum_kernel(
        const float* __restrict__ pitch, float* __restrict__ y,
        const float* __restrict__ wavetables, const float* __restrict__ fir_h,
        float* __restrict__ wt4) {
    __shared__ float s_pad[WT_LEN_ + 2 * N_REFL_];
    __shared__ float s_h[FIR_TAPS_];
    const int b = blockIdx.y, bx = blockIdx.x, t = threadIdx.x;

    const bool do_fir = (b == 0) && (bx < N_WT_);   // uniform per block
    if (do_fir) {
        if (t < FIR_TAPS_) s_h[t] = fir_h[t];
        for (int j = t; j < WT_LEN_ + 2 * N_REFL_; j += TPB) {
            int src = (j + WT_LEN_ - N_REFL_) % WT_LEN_;
            s_pad[j] = wavetables[bx * WT_LEN_ + src];
        }
        __syncthreads();   // block-uniform condition: safe
        for (int i = t; i < WT_LEN_; i += TPB) {   // i = t and t+256
            float acc = 0.0f;
#pragma unroll
            for (int tap = 0; tap < FIR_TAPS_; ++tap)
                acc = fmaf(s_h[tap], s_pad[i + tap], acc);
            wt4[i * WROW + bx] = acc;
            if (i == 0) wt4[WT_LEN_ * WROW + bx] = acc;  // dup row 0 at row 512
        }
    }

    const int g = bx * 256 + t;
    if (g < NG0) {
        const float4* p4 = (const float4*)(pitch + (size_t)b * L_ + (size_t)g * 16);
        float4 v0 = p4[0], v1 = p4[1], v2 = p4[2], v3 = p4[3];
        float xs[16] = {v0.x, v0.y, v0.z, v0.w, v1.x, v1.y, v1.z, v1.w,
                        v2.x, v2.y, v2.z, v2.w, v3.x, v3.y, v3.z, v3.w};
        float acc = 0.0f;
#pragma unroll
        for (int i = 0; i < 16; ++i) {
            float inc = INCF * xs[i];
            asm("" : "+v"(inc));       // forbid mul+add contraction
            acc += inc;                // sequential f32 fold
        }
        y[b * NG0 + g] = acc;
    }
}

// ---------------------------------------------------------------------------
// Kernel 2: per-row hierarchical scan (base 16, sequential inner folds),
// running folds == bit-identical to per-endpoint from-scratch folds.
// Materializes S1 so synth pays one near-broadcast coalesced load per sample.
// ---------------------------------------------------------------------------
__global__ __launch_bounds__(TPS) void scan_kernel(
        const float* __restrict__ y, float* __restrict__ S1) {
    __shared__ __align__(16) float s_y[NG0];    // 40 KB
    __shared__ __align__(16) float s_S1[NG0];   // 40 KB
    __shared__ float s_z[NG1];
    __shared__ float s_S2[NG1];
    __shared__ float s_w[NG2], s_S3[NG2];
    __shared__ float s_v[NG3], s_S4[NG3];
    const int b = blockIdx.x, t = threadIdx.x;
    const float* yrow = y + (size_t)b * NG0;
    {   // vectorized row load (NG0 even, row byte offset % 8 == 0)
        const float2* src = (const float2*)yrow;
        float2* dst = (float2*)s_y;
        for (int i = t; i < NG0 / 2; i += TPS) dst[i] = src[i];
    }
    __syncthreads();
    for (int j = t; j < NG1; j += TPS) {
        float a = 0.0f;
        for (int i = 0; i < 16; ++i) a += s_y[16 * j + i];
        s_z[j] = a;
    }
    __syncthreads();
    if (t < NG2) {
        float a = 0.0f;
        int hi = min(16 * t + 16, NG1);
        for (int i = 16 * t; i < hi; ++i) a += s_z[i];
        s_w[t] = a;
    }
    __syncthreads();
    if (t < NG3) {
        float a = 0.0f;
        int hi = min(16 * t + 16, NG2);
        for (int i = 16 * t; i < hi; ++i) a += s_w[i];
        s_v[t] = a;
    }
    __syncthreads();
    if (t == 0) {
        float run = 0.0f;
        for (int m = 0; m < NG3; ++m) { run += s_v[m]; s_S4[m] = run; }
    }
    __syncthreads();
    if (t < NG2) {
        float a = 0.0f;
        for (int i = (t >> 4) << 4; i <= t; ++i) a += s_w[i];
        if (t >= 16) a = a + s_S4[(t >> 4) - 1];
        s_S3[t] = a;
    }
    __syncthreads();
    if (t < NG2) {
        float r = 0.0f;
        float carry = (t > 0) ? s_S3[t - 1] : 0.0f;
        int hi = min(16 * t + 16, NG1);
        for (int k = 16 * t; k < hi; ++k) {
            r += s_z[k];
            s_S2[k] = (t > 0) ? r + carry : r;
        }
    }
    __syncthreads();
    for (int j = t; j < NG1; j += TPS) {
        float r = 0.0f;
        float carry = (j > 0) ? s_S2[j - 1] : 0.0f;
        for (int k = 0; k < 16; ++k) {
            r += s_y[16 * j + k];
            s_S1[16 * j + k] = (j > 0) ? r + carry : r;
        }
    }
    __syncthreads();
    float* S1row = S1 + (size_t)b * NG0;
    {   // vectorized row store
        const float2* src = (const float2*)s_S1;
        float2* dst = (float2*)S1row;
        for (int i = t; i < NG0 / 2; i += TPS) dst[i] = src[i];
    }
}

// ---------------------------------------------------------------------------
// Kernel 3: synth — barrier-free, LDS-free, one sample per thread
// (grid 625 x 16). The 24.6 KB padded interleaved wavetable stays
// L1/L2-resident across all 10000 blocks; rows lo,lo+1 = floats
// [lo*12, lo*12+22) at a 16B-aligned base -> 6x float4 (was 10x float2:
// 40% fewer divergent-gather instructions in the L1 path). Pad floats
// 10-11 of each row are loaded but never used. All global loads issued
// up-front; 40000 waves of pure-streaming TLP hide HBM and L1/L2 latency.
// Fold via wave shuffles (+0.0f predicated adds exact: all partials > 0
// since pitch >= 100 Hz).
// ---------------------------------------------------------------------------
__global__ __launch_bounds__(TPB) void synth_kernel(
        const float* __restrict__ pitch,
        const float* __restrict__ envelope,
        const float* __restrict__ attention,
        const float* __restrict__ wt4,
        const float* __restrict__ S1,
        float* __restrict__ out) {
    const int b = blockIdx.y, cb = blockIdx.x, t = threadIdx.x;
    const int    l = cb * TPB + t;
    const size_t g = (size_t)b * L_ + l;

    // --- issue every independent global load up-front ---
    const float pv  = pitch[g];          // own increment source
    const float p0  = pitch[l];          // batch-row-0 quirk (increment[0])
    const float env = envelope[g];
    const int   g0  = l >> 4;
    const float carry = (g0 > 0) ? S1[(size_t)b * NG0 + g0 - 1] : 0.0f;
    const float2* ap = (const float2*)(attention + g * (size_t)N_WT_);
    float2 a01 = ap[0], a23 = ap[1], a45 = ap[2], a67 = ap[3], a89 = ap[4];

    const int lane  = t & 63;
    const int r16   = lane & 15;
    const int sbase = lane & ~15;

    float x = INCF * pv;  // f32 increment, separately rounded
    // sequential in-group-of-16 fold via shuffles (bit-exact association)
    float acc = 0.0f;
#pragma unroll
    for (int k = 0; k < 16; ++k) {
        float v = __shfl(x, sbase + k, 64);
        acc += (k <= r16) ? v : 0.0f;
    }
    if (g0 > 0) acc = acc + carry;       // carry add

    float idx = acc - INCF * p0;         // minus increment[0] (batch row 0)
    float r = fmodf(idx, 512.0f);        // lax.rem (exact for y=512)
    if (r < 0.0f) r += 512.0f;           // jnp.remainder sign fixup
    if (512.0f - r < 1e-5f) r = 0.0f;    // the reference's snap
    float fl = floorf(r);
    float alpha = r - fl;
    int lo = (int)fl;

    // rows lo (floats 0-9 of pw[0..2]) and lo+1 (floats 0-9 of pw[3..5])
    const float4* pw = (const float4*)(wt4 + lo * WROW);
    float4 q0 = pw[0], q1 = pw[1], q2 = pw[2];
    float4 r0 = pw[3], r1 = pw[4], r2 = pw[5];
    float loV[10] = {q0.x, q0.y, q0.z, q0.w, q1.x, q1.y, q1.z, q1.w, q2.x, q2.y};
    float hiV[10] = {r0.x, r0.y, r0.z, r0.w, r1.x, r1.y, r1.z, r1.w, r2.x, r2.y};
    float a[10] = {a01.x, a01.y, a23.x, a23.y, a45.x, a45.y,
                   a67.x, a67.y, a89.x, a89.y};

    float a0 = 0.0f;
#pragma unroll
    for (int w = 0; w < N_WT_; ++w)
        a0 += a[w] * (loV[w] + alpha * (hiV[w] - loV[w]));
    out[g] = a0 * env;
}

// ---------------------------------------------------------------------------
extern "C" void kernel_launch(void* const* d_in, const int* in_sizes, int n_in,
                              void* d_out, int out_size, void* d_ws, size_t ws_size,
                              hipStream_t stream) {
    const float* pitch      = (const float*)d_in[0];  // (B, L, 1)
    const float* envelope   = (const float*)d_in[1];  // (B, L, 1)
    const float* attention  = (const float*)d_in[2];  // (B, L, 10)
    const float* wavetables = (const float*)d_in[3];  // (10, 512)
    const float* fir_h      = (const float*)d_in[4];  // (31,)
    float*       out        = (float*)d_out;          // (B, L, 1)

    char*  ws  = (char*)d_ws;
    float* wt4 = (float*)(ws);                         // 513*12*4 = 24624 B
    float* y   = (float*)(ws + 32768);                 // 16*10000*4 = 640 KB
    float* S1  = (float*)(ws + 32768 + 655360);        // 640 KB

    ysum_kernel<<<dim3(40, B_), dim3(TPB), 0, stream>>>(
        pitch, y, wavetables, fir_h, wt4);
    scan_kernel<<<dim3(B_), dim3(TPS), 0, stream>>>(y, S1);
    synth_kernel<<<dim3(NG1, B_), dim3(TPB), 0, stream>>>(
        pitch, envelope, attention, wt4, S1, out);
}

// Round 6
// 184.832 us; speedup vs baseline: 1.0287x; 1.0277x over previous
//
#include <hip/hip_runtime.h>

#define N_WT_     10
#define WT_LEN_   512
#define FIR_TAPS_ 31
#define N_REFL_   15
#define B_        16
#define L_        160000

constexpr int   TPB   = 256;
constexpr int   TPS   = 1024;          // scan block size
constexpr float INCF  = 0.032f;        // f32(512/16000), jax weak-typed scalar
constexpr int   NG0   = L_ / 16;       // 10000 level-0 groups (of 16 samples)
constexpr int   NG1   = NG0 / 16;      // 625 level-1 groups
constexpr int   NG2   = 40;            // ceil(625/16), pad 625->640
constexpr int   NG3   = 3;             // ceil(40/16),  pad 40->48

// ---------------------------------------------------------------------------
// Kernel 1: level-0 group sums, LDS-free for the sums. Each thread owns one
// group of 16: 4x float4 loads (lane-private 64B line => perfectly
// line-coalesced), then the same sequential f32 fold. The empty asm() blocks
// fp-contraction so the INCF*pitch multiply stays separately rounded.
// FIR filter fused into the first 10 blocks of row b==0; wt2 written
// INTERLEAVED: wt2[i*10+w], row 512 duplicating row 0 (20520 B).
// ---------------------------------------------------------------------------
__global__ __launch_bounds__(TPB) void ysum_kernel(
        const float* __restrict__ pitch, float* __restrict__ y,
        const float* __restrict__ wavetables, const float* __restrict__ fir_h,
        float* __restrict__ wt2) {
    __shared__ float s_pad[WT_LEN_ + 2 * N_REFL_];
    __shared__ float s_h[FIR_TAPS_];
    const int b = blockIdx.y, bx = blockIdx.x, t = threadIdx.x;

    const bool do_fir = (b == 0) && (bx < N_WT_);   // uniform per block
    if (do_fir) {
        if (t < FIR_TAPS_) s_h[t] = fir_h[t];
        for (int j = t; j < WT_LEN_ + 2 * N_REFL_; j += TPB) {
            int src = (j + WT_LEN_ - N_REFL_) % WT_LEN_;
            s_pad[j] = wavetables[bx * WT_LEN_ + src];
        }
        __syncthreads();   // block-uniform condition: safe
        for (int i = t; i < WT_LEN_; i += TPB) {   // i = t and t+256
            float acc = 0.0f;
#pragma unroll
            for (int tap = 0; tap < FIR_TAPS_; ++tap)
                acc = fmaf(s_h[tap], s_pad[i + tap], acc);
            wt2[i * N_WT_ + bx] = acc;
            if (i == 0) wt2[WT_LEN_ * N_WT_ + bx] = acc;  // dup row 0 at row 512
        }
    }

    const int g = bx * 256 + t;
    if (g < NG0) {
        const float4* p4 = (const float4*)(pitch + (size_t)b * L_ + (size_t)g * 16);
        float4 v0 = p4[0], v1 = p4[1], v2 = p4[2], v3 = p4[3];
        float xs[16] = {v0.x, v0.y, v0.z, v0.w, v1.x, v1.y, v1.z, v1.w,
                        v2.x, v2.y, v2.z, v2.w, v3.x, v3.y, v3.z, v3.w};
        float acc = 0.0f;
#pragma unroll
        for (int i = 0; i < 16; ++i) {
            float inc = INCF * xs[i];
            asm("" : "+v"(inc));       // forbid mul+add contraction
            acc += inc;                // sequential f32 fold
        }
        y[b * NG0 + g] = acc;
    }
}

// ---------------------------------------------------------------------------
// Kernel 2: per-row hierarchical scan (base 16, sequential inner folds),
// running folds == bit-identical to per-endpoint from-scratch folds.
// ---------------------------------------------------------------------------
__global__ __launch_bounds__(TPS) void scan_kernel(
        const float* __restrict__ y, float* __restrict__ S1) {
    __shared__ __align__(16) float s_y[NG0];    // 40 KB
    __shared__ __align__(16) float s_S1[NG0];   // 40 KB
    __shared__ float s_z[NG1];
    __shared__ float s_S2[NG1];
    __shared__ float s_w[NG2], s_S3[NG2];
    __shared__ float s_v[NG3], s_S4[NG3];
    const int b = blockIdx.x, t = threadIdx.x;
    const float* yrow = y + (size_t)b * NG0;
    {   // vectorized row load (NG0 even, row byte offset % 8 == 0)
        const float2* src = (const float2*)yrow;
        float2* dst = (float2*)s_y;
        for (int i = t; i < NG0 / 2; i += TPS) dst[i] = src[i];
    }
    __syncthreads();
    for (int j = t; j < NG1; j += TPS) {
        float a = 0.0f;
        for (int i = 0; i < 16; ++i) a += s_y[16 * j + i];
        s_z[j] = a;
    }
    __syncthreads();
    if (t < NG2) {
        float a = 0.0f;
        int hi = min(16 * t + 16, NG1);
        for (int i = 16 * t; i < hi; ++i) a += s_z[i];
        s_w[t] = a;
    }
    __syncthreads();
    if (t < NG3) {
        float a = 0.0f;
        int hi = min(16 * t + 16, NG2);
        for (int i = 16 * t; i < hi; ++i) a += s_w[i];
        s_v[t] = a;
    }
    __syncthreads();
    if (t == 0) {
        float run = 0.0f;
        for (int m = 0; m < NG3; ++m) { run += s_v[m]; s_S4[m] = run; }
    }
    __syncthreads();
    if (t < NG2) {
        float a = 0.0f;
        for (int i = (t >> 4) << 4; i <= t; ++i) a += s_w[i];
        if (t >= 16) a = a + s_S4[(t >> 4) - 1];
        s_S3[t] = a;
    }
    __syncthreads();
    if (t < NG2) {
        float r = 0.0f;
        float carry = (t > 0) ? s_S3[t - 1] : 0.0f;
        int hi = min(16 * t + 16, NG1);
        for (int k = 16 * t; k < hi; ++k) {
            r += s_z[k];
            s_S2[k] = (t > 0) ? r + carry : r;
        }
    }
    __syncthreads();
    for (int j = t; j < NG1; j += TPS) {
        float r = 0.0f;
        float carry = (j > 0) ? s_S2[j - 1] : 0.0f;
        for (int k = 0; k < 16; ++k) {
            r += s_y[16 * j + k];
            s_S1[16 * j + k] = (j > 0) ? r + carry : r;
        }
    }
    __syncthreads();
    float* S1row = S1 + (size_t)b * NG0;
    {   // vectorized row store
        const float2* src = (const float2*)s_S1;
        float2* dst = (float2*)S1row;
        for (int i = t; i < NG0 / 2; i += TPS) dst[i] = src[i];
    }
}

// ---------------------------------------------------------------------------
// Kernel 3: synth — round-2 structure (one sample per thread, grid 625 x 16,
// direct global wavetable gather) with ONE change: the block's 10 KB
// attention slab is staged into LDS with perfectly coalesced float4 loads
// (40 line-touches/wave instead of 200 for the 40B-strided float2 pattern),
// then read back per-thread as 5x ds_read_b64 (~4-way bank conflicts, cheap).
// Scalar loads still issue before staging so HBM latency hides under it.
// Values and all arithmetic bit-identical to the 187.2 us round-2 kernel.
// ---------------------------------------------------------------------------
__global__ __launch_bounds__(TPB) void synth_kernel(
        const float* __restrict__ pitch,
        const float* __restrict__ envelope,
        const float* __restrict__ attention,
        const float* __restrict__ wt2,
        const float* __restrict__ S1,
        float* __restrict__ out) {
    __shared__ __align__(16) float s_at[TPB * N_WT_];  // 10240 B
    const int b = blockIdx.y, cb = blockIdx.x, t = threadIdx.x;
    const int    l = cb * TPB + t;
    const size_t g = (size_t)b * L_ + l;

    // --- issue independent scalar loads up-front ---
    const float pv  = pitch[g];          // own increment source
    const float p0  = pitch[l];          // batch-row-0 quirk (increment[0])
    const float env = envelope[g];
    const int   g0  = l >> 4;
    const float carry = (g0 > 0) ? S1[(size_t)b * NG0 + g0 - 1] : 0.0f;

    // --- coalesced attention stage: 640 float4s, 2.5 per thread ---
    {
        const float4* asrc = (const float4*)(attention
                + ((size_t)b * L_ + (size_t)cb * TPB) * N_WT_);
        float4* adst = (float4*)s_at;
        adst[t]       = asrc[t];
        adst[t + 256] = asrc[t + 256];
        if (t < (TPB * N_WT_) / 4 - 512) adst[t + 512] = asrc[t + 512];
    }
    __syncthreads();  // the only barrier

    const int lane  = t & 63;
    const int r16   = lane & 15;
    const int sbase = lane & ~15;

    float x = INCF * pv;  // f32 increment, separately rounded
    // sequential in-group-of-16 fold via shuffles (bit-exact association;
    // +0.0f predicated adds exact: all partials > 0 since pitch >= 100 Hz)
    float acc = 0.0f;
#pragma unroll
    for (int k = 0; k < 16; ++k) {
        float v = __shfl(x, sbase + k, 64);
        acc += (k <= r16) ? v : 0.0f;
    }
    if (g0 > 0) acc = acc + carry;       // carry add

    float idx = acc - INCF * p0;         // minus increment[0] (batch row 0)
    float r = fmodf(idx, 512.0f);        // lax.rem (exact for y=512)
    if (r < 0.0f) r += 512.0f;           // jnp.remainder sign fixup
    if (512.0f - r < 1e-5f) r = 0.0f;    // the reference's snap
    float fl = floorf(r);
    float alpha = r - fl;
    int lo = (int)fl;

    // rows lo, lo+1 = 20 contiguous floats in L1/L2-resident wt2
    const float2* pw = (const float2*)(wt2 + lo * N_WT_);
    float2 q0 = pw[0], q1 = pw[1], q2 = pw[2], q3 = pw[3], q4 = pw[4];
    float2 q5 = pw[5], q6 = pw[6], q7 = pw[7], q8 = pw[8], q9 = pw[9];
    float loV[10] = {q0.x, q0.y, q1.x, q1.y, q2.x, q2.y, q3.x, q3.y, q4.x, q4.y};
    float hiV[10] = {q5.x, q5.y, q6.x, q6.y, q7.x, q7.y, q8.x, q8.y, q9.x, q9.y};

    // per-thread attention from LDS (same values as the old global float2s)
    const float2* pa = (const float2*)(s_at + t * N_WT_);
    float2 a01 = pa[0], a23 = pa[1], a45 = pa[2], a67 = pa[3], a89 = pa[4];
    float a[10] = {a01.x, a01.y, a23.x, a23.y, a45.x, a45.y,
                   a67.x, a67.y, a89.x, a89.y};

    float a0 = 0.0f;
#pragma unroll
    for (int w = 0; w < N_WT_; ++w)
        a0 += a[w] * (loV[w] + alpha * (hiV[w] - loV[w]));
    out[g] = a0 * env;
}

// ---------------------------------------------------------------------------
extern "C" void kernel_launch(void* const* d_in, const int* in_sizes, int n_in,
                              void* d_out, int out_size, void* d_ws, size_t ws_size,
                              hipStream_t stream) {
    const float* pitch      = (const float*)d_in[0];  // (B, L, 1)
    const float* envelope   = (const float*)d_in[1];  // (B, L, 1)
    const float* attention  = (const float*)d_in[2];  // (B, L, 10)
    const float* wavetables = (const float*)d_in[3];  // (10, 512)
    const float* fir_h      = (const float*)d_in[4];  // (31,)
    float*       out        = (float*)d_out;          // (B, L, 1)

    char*  ws  = (char*)d_ws;
    float* wt2 = (float*)(ws);                         // 20520 B (reserve 32 KiB)
    float* y   = (float*)(ws + 32768);                 // 16*10000*4 = 640 KB
    float* S1  = (float*)(ws + 32768 + 655360);        // 640 KB

    ysum_kernel<<<dim3(40, B_), dim3(TPB), 0, stream>>>(
        pitch, y, wavetables, fir_h, wt2);
    scan_kernel<<<dim3(B_), dim3(TPS), 0, stream>>>(y, S1);
    synth_kernel<<<dim3(NG1, B_), dim3(TPB), 0, stream>>>(
        pitch, envelope, attention, wt2, S1, out);
}